// Round 11
// baseline (206.822 us; speedup 1.0000x reference)
//
#include <hip/hip_runtime.h>
#include <hip/hip_bf16.h>
#include <math.h>

typedef __attribute__((ext_vector_type(8))) short bf16x8;
typedef __attribute__((ext_vector_type(4))) float f32x4;

#define D_MODEL 2048
#define R_DIM 512
#define N_HEADS 16
#define D_K 32
#define B_SZ 2
#define SEQ 2048
#define M_ROWS (B_SZ * SEQ)
#define N_QKV 1536
// log2(e) / sqrt(D_K) — folded into Wq/bq so attention does raw exp2(Q.K)
#define QSCALE 0.2550627231338903f

// async global->LDS 16B DMA (lane i lands at lds_base + i*16)
__device__ __forceinline__ void dma16(const void* g, void* l)
{
    __builtin_amdgcn_global_load_lds(
        (const __attribute__((address_space(1))) void*)g,
        (__attribute__((address_space(3))) void*)l, 16, 0, 0);
}

// pack two f32 -> one dword of 2 bf16 (lo = first arg). No builtin on gfx950.
__device__ __forceinline__ unsigned cvt_pk_bf16(float lo, float hi)
{
    unsigned r;
    asm("v_cvt_pk_bf16_f32 %0, %1, %2" : "=v"(r) : "v"(lo), "v"(hi));
    return r;
}

// ---------------------------------------------------------------------------
// One-time f32 -> bf16 conversion. 4 loads in flight per thread.
// by: 0 Wq*QSCALE  1 Wk  2 Wv  3 Wo  4 x  5 bias_qkv & mask bias
// ---------------------------------------------------------------------------
__global__ __launch_bounds__(256) void cvt_inputs(
    const float* __restrict__ x,  __hip_bfloat16* __restrict__ xb,
    const float* __restrict__ Wq, const float* __restrict__ Wk,
    const float* __restrict__ Wv, const float* __restrict__ Wo,
    __hip_bfloat16* __restrict__ Wqkvb, __hip_bfloat16* __restrict__ Wob,
    const float* __restrict__ bq, const float* __restrict__ bk,
    const float* __restrict__ bv, float* __restrict__ bias_qkv,
    const int* __restrict__ mask, float* __restrict__ mbias)
{
    const int by = blockIdx.y;
    const int tid = blockIdx.x * blockDim.x + threadIdx.x;
    const int nthr = gridDim.x * blockDim.x;   // 65536
    if (by == 5) {
        for (int i = tid; i < N_QKV; i += nthr) {
            float v = (i < 512) ? bq[i] * QSCALE
                    : (i < 1024) ? bk[i - 512] : bv[i - 1024];
            bias_qkv[i] = v;
        }
        for (int i = tid; i < B_SZ * SEQ; i += nthr)
            mbias[i] = mask[i] ? 0.0f : -1e30f;
        return;
    }
    const float* src; __hip_bfloat16* dst; float sc = 1.0f; int n;
    switch (by) {
      case 0: src = Wq; dst = Wqkvb; sc = QSCALE; n = R_DIM * D_MODEL; break;
      case 1: src = Wk; dst = Wqkvb + (size_t)R_DIM * D_MODEL; n = R_DIM * D_MODEL; break;
      case 2: src = Wv; dst = Wqkvb + (size_t)2 * R_DIM * D_MODEL; n = R_DIM * D_MODEL; break;
      case 3: src = Wo; dst = Wob; n = D_MODEL * R_DIM; break;
      default: src = x;  dst = xb;  n = M_ROWS * D_MODEL; break;
    }
    const float4* s4 = (const float4*)src;
    ushort4* d4 = (ushort4*)dst;
    const int n4 = n >> 2;          // 262144 (W) or 4194304 (x)
    const int step = nthr * 4;      // 262144
    for (int i0 = tid; i0 < n4; i0 += step) {
        float4 f0 = s4[i0];
        float4 f1 = s4[i0 + nthr];
        float4 f2 = s4[i0 + 2 * nthr];
        float4 f3 = s4[i0 + 3 * nthr];
        union { ushort4 u; __hip_bfloat16 h[4]; } r0, r1, r2, r3;
        r0.h[0] = __float2bfloat16(f0.x * sc); r0.h[1] = __float2bfloat16(f0.y * sc);
        r0.h[2] = __float2bfloat16(f0.z * sc); r0.h[3] = __float2bfloat16(f0.w * sc);
        r1.h[0] = __float2bfloat16(f1.x * sc); r1.h[1] = __float2bfloat16(f1.y * sc);
        r1.h[2] = __float2bfloat16(f1.z * sc); r1.h[3] = __float2bfloat16(f1.w * sc);
        r2.h[0] = __float2bfloat16(f2.x * sc); r2.h[1] = __float2bfloat16(f2.y * sc);
        r2.h[2] = __float2bfloat16(f2.z * sc); r2.h[3] = __float2bfloat16(f2.w * sc);
        r3.h[0] = __float2bfloat16(f3.x * sc); r3.h[1] = __float2bfloat16(f3.y * sc);
        r3.h[2] = __float2bfloat16(f3.z * sc); r3.h[3] = __float2bfloat16(f3.w * sc);
        d4[i0]            = r0.u;
        d4[i0 + nthr]     = r1.u;
        d4[i0 + 2 * nthr] = r2.u;
        d4[i0 + 3 * nthr] = r3.u;
    }
}

// ---------------------------------------------------------------------------
// DMA-staged GEMM: C[M,N] = A[M,K] @ W[N,K]^T + bias[N]  (bf16 MFMA, f32 acc)
// BM=128, BN=64, BK=64. 4 waves, wave-tile 64Mx32N (4x2 accs, 16 MFMA/iter).
// EXACT R5 form — cross-round ledger (R5/R6/R7/R9): beats every 128x128 /
// dbuf / counted-vmcnt variant at this problem size (grid residency wins).
// ---------------------------------------------------------------------------
template<bool OUT_BF16>
__global__ __launch_bounds__(256, 4) void gemm_dma(
    const __hip_bfloat16* __restrict__ A,
    const __hip_bfloat16* __restrict__ W,
    const float* __restrict__ bias,
    void* __restrict__ Cv,
    int N, int K)
{
    __shared__ __hip_bfloat16 As[128 * 64];   // 16 KB, slot = row*8 + (c^(row&7))
    __shared__ __hip_bfloat16 Bs[64 * 64];    // 8 KB

    const int tid = threadIdx.x, lane = tid & 63, w = tid >> 6;
    const int l15 = lane & 15, q = lane >> 4;
    const int bm = blockIdx.y * 128, bn = blockIdx.x * 64;
    const int m_off = (w & 1) * 64, n_off = (w >> 1) * 32;

    const int lrow = lane >> 3;            // 0..7
    const int lc   = (lane & 7) ^ lrow;    // swizzled 16B-chunk within row

    f32x4 acc[4][2] = {};

    for (int kt = 0; kt < K; kt += 64) {
        if (kt) __syncthreads();           // all waves done reading prev tile
        #pragma unroll
        for (int j = 0; j < 4; j++) {      // A: 128 rows, 8 rows per issue
            int row = (w * 4 + j) * 8 + lrow;
            dma16(&A[(size_t)(bm + row) * K + kt + lc * 8], &As[(w * 4 + j) * 512]);
        }
        #pragma unroll
        for (int j = 0; j < 2; j++) {      // B: 64 rows
            int row = (w * 2 + j) * 8 + lrow;
            dma16(&W[(size_t)(bn + row) * K + kt + lc * 8], &Bs[(w * 2 + j) * 512]);
        }
        __syncthreads();                   // vmcnt drain + barrier

        #pragma unroll
        for (int ks = 0; ks < 2; ks++) {
            bf16x8 af[4], bf[2];
            #pragma unroll
            for (int t = 0; t < 4; t++) {
                int row = m_off + t * 16 + l15;
                af[t] = *(const bf16x8*)&As[row * 64 + (((ks * 4 + q) ^ (l15 & 7)) * 8)];
            }
            #pragma unroll
            for (int u = 0; u < 2; u++) {
                int row = n_off + u * 16 + l15;
                bf[u] = *(const bf16x8*)&Bs[row * 64 + (((ks * 4 + q) ^ (l15 & 7)) * 8)];
            }
            #pragma unroll
            for (int mt = 0; mt < 4; mt++)
                #pragma unroll
                for (int nt = 0; nt < 2; nt++)
                    acc[mt][nt] = __builtin_amdgcn_mfma_f32_16x16x32_bf16(
                        af[mt], bf[nt], acc[mt][nt], 0, 0, 0);
        }
    }

    #pragma unroll
    for (int mt = 0; mt < 4; mt++) {
        #pragma unroll
        for (int nt = 0; nt < 2; nt++) {
            int gm = bm + m_off + mt * 16 + q * 4;
            int gn = bn + n_off + nt * 16 + l15;
            float bv = bias[gn];
            #pragma unroll
            for (int r = 0; r < 4; r++) {
                float v = acc[mt][nt][r] + bv;
                if (OUT_BF16)
                    ((__hip_bfloat16*)Cv)[(size_t)(gm + r) * N + gn] = __float2bfloat16(v);
                else
                    ((float*)Cv)[(size_t)(gm + r) * N + gn] = v;
            }
        }
    }
}

// ---------------------------------------------------------------------------
// Flash attention v11 = flash8 (QBLK 128, 2 q-chains, grid 512 = the proven
// TLP x ILP optimum: 64->53us, 128->40us, 256->64us) + KVBLK 64 -> 128.
// Per-kv costs unchanged; per-tile overheads halve: 32 -> 16 barriers,
// prefetch blocks halved, loop overhead halved. sigma window mapping extends
// per 64-window (second window at col offset +64); Vt stride 136 == 72
// (mod 32 banks) -> identical conflict profile. QK^T/exp split into two
// half-phases to keep the sc transient at 32 VGPR.
// launch_bounds(256,2): cap 256 -> spill impossible (R3 lesson); occupancy
// is grid-limited at 2 blocks/CU so the looser bound costs nothing.
// ---------------------------------------------------------------------------
__global__ __launch_bounds__(256, 2) void flash_attn11(
    const __hip_bfloat16* __restrict__ QKV,
    const float* __restrict__ mbias,
    __hip_bfloat16* __restrict__ O)
{
    __shared__ __hip_bfloat16 Ks[2][128 * 40];   // 20 KB
    __shared__ __hip_bfloat16 Vt[2][32 * 136];   // 17 KB (sigma-permuted cols)

    const int tid = threadIdx.x, lane = tid & 63, w = tid >> 6;
    const int l15 = lane & 15, qg = lane >> 4;

    // XCD-chunked swizzle (512 % 8 == 0 -> bijective)
    const int nwg = (int)gridDim.x;
    const int swz = ((int)blockIdx.x & 7) * (nwg >> 3) + ((int)blockIdx.x >> 3);
    const int qt = swz & 15;
    const int h  = (swz >> 4) & 15;
    const int b  = swz >> 8;
    const int q0 = qt * 128;

    // Q fragments (B-operand of swapped QK^T): rows q0+w*32+{l15, 16+l15}
    const bf16x8 qa0 = *(const bf16x8*)
        &QKV[(size_t)(b * SEQ + q0 + w * 32 + l15) * N_QKV + h * D_K + qg * 8];
    const bf16x8 qa1 = *(const bf16x8*)
        &QKV[(size_t)(b * SEQ + q0 + w * 32 + 16 + l15) * N_QKV + h * D_K + qg * 8];

    const int kv_k = tid >> 2, d0_k = (tid & 3) * 8;   // K staging: rows kv_k, kv_k+64
    const int kv_v = tid & 63, d0_v = (tid >> 6) * 8;  // V staging: cols kv_v, kv_v+64
    // sigma-permuted V column within a 64-window: kv = 32a+16hi+4g+r -> 32a+8g+4hi+r
    const int scol_v = (kv_v & 32) + ((kv_v >> 2) & 3) * 8
                     + ((kv_v >> 4) & 1) * 4 + (kv_v & 3);

    const __hip_bfloat16* Kp = QKV + (size_t)b * SEQ * N_QKV + R_DIM + h * D_K;
    const __hip_bfloat16* Vp = QKV + (size_t)b * SEQ * N_QKV + 2 * R_DIM + h * D_K;
    const float* mb_base = mbias + b * SEQ;

    f32x4 oaccA[2] = {};   // qfrag0: rows w*32 + qg*4+r
    f32x4 oaccB[2] = {};   // qfrag1: rows w*32 + 16 + qg*4+r
    float rsum0 = 0.f, rsum1 = 0.f;

    uint4 kregA[2], kregB[2], vregA[2], vregB[2];

    // prologue: tile 0 (128 kv) into register set A
    kregA[0] = *(const uint4*)&Kp[(size_t)kv_k * N_QKV + d0_k];
    kregA[1] = *(const uint4*)&Kp[(size_t)(kv_k + 64) * N_QKV + d0_k];
    vregA[0] = *(const uint4*)&Vp[(size_t)kv_v * N_QKV + d0_v];
    vregA[1] = *(const uint4*)&Vp[(size_t)(kv_v + 64) * N_QKV + d0_v];

#define FA_EXP(SC, MB, PA, U0, U1, RS)                                          \
    {                                                                           \
        float p0 = __builtin_amdgcn_exp2f(SC[0] + MB.x);                        \
        float p1 = __builtin_amdgcn_exp2f(SC[1] + MB.y);                        \
        float p2 = __builtin_amdgcn_exp2f(SC[2] + MB.z);                        \
        float p3 = __builtin_amdgcn_exp2f(SC[3] + MB.w);                        \
        RS += (p0 + p1) + (p2 + p3);                                            \
        PA.u[U0] = cvt_pk_bf16(p0, p1);                                         \
        PA.u[U1] = cvt_pk_bf16(p2, p3);                                         \
    }

// one half-QK^T (4 nt windows starting at NT0) for both chains
#define FA_QKT_HALF(BUF, NT0, SCA, SCB)                                         \
    __builtin_amdgcn_s_setprio(1);                                              \
    _Pragma("unroll")                                                           \
    for (int nt = 0; nt < 4; nt++) {                                            \
        bf16x8 kb = *(const bf16x8*)&Ks[BUF][((NT0 + nt) * 16 + l15) * 40 + qg * 8]; \
        f32x4 z = {};                                                           \
        SCA[nt] = __builtin_amdgcn_mfma_f32_16x16x32_bf16(kb, qa0, z, 0, 0, 0); \
        SCB[nt] = __builtin_amdgcn_mfma_f32_16x16x32_bf16(kb, qa1, z, 0, 0, 0); \
    }                                                                           \
    __builtin_amdgcn_s_setprio(0);

#define FA_ITER(KT, BUF, KREG, VREG, KREGN, VREGN)                              \
    {                                                                           \
        /* stage current 128-kv tile (regs loaded last iter) into LDS[BUF] */   \
        *(uint4*)&Ks[BUF][kv_k * 40 + d0_k] = KREG[0];                          \
        *(uint4*)&Ks[BUF][(kv_k + 64) * 40 + d0_k] = KREG[1];                   \
        { union { uint4 u; __hip_bfloat16 hv[8]; } vv0, vv1;                    \
          vv0.u = VREG[0]; vv1.u = VREG[1];                                     \
          _Pragma("unroll")                                                     \
          for (int j = 0; j < 8; j++) {                                         \
              Vt[BUF][(d0_v + j) * 136 + scol_v]      = vv0.hv[j];              \
              Vt[BUF][(d0_v + j) * 136 + 64 + scol_v] = vv1.hv[j];              \
          } }                                                                   \
        __syncthreads();                                                        \
        /* mask bias for 128 kv */                                              \
        float4 mb[8];                                                           \
        _Pragma("unroll")                                                       \
        for (int i = 0; i < 8; i++)                                             \
            mb[i] = *(const float4*)&mb_base[(KT) + i * 16 + qg * 4];           \
        /* prefetch next 128-kv tile: full iteration of compute covers it */    \
        if ((KT) + 128 < SEQ) {                                                 \
            KREGN[0] = *(const uint4*)&Kp[(size_t)((KT) + 128 + kv_k) * N_QKV + d0_k]; \
            KREGN[1] = *(const uint4*)&Kp[(size_t)((KT) + 192 + kv_k) * N_QKV + d0_k]; \
            VREGN[0] = *(const uint4*)&Vp[(size_t)((KT) + 128 + kv_v) * N_QKV + d0_v]; \
            VREGN[1] = *(const uint4*)&Vp[(size_t)((KT) + 192 + kv_v) * N_QKV + d0_v]; \
        }                                                                       \
        union { unsigned u[4]; bf16x8 v; } paA[4], paB[4];                      \
        { /* first half: kv [0,64) */                                           \
            f32x4 sa[4], sb[4];                                                 \
            FA_QKT_HALF(BUF, 0, sa, sb)                                         \
            FA_EXP(sa[0], mb[0], paA[0], 0, 1, rsum0)                           \
            FA_EXP(sa[1], mb[1], paA[0], 2, 3, rsum0)                           \
            FA_EXP(sa[2], mb[2], paA[1], 0, 1, rsum0)                           \
            FA_EXP(sa[3], mb[3], paA[1], 2, 3, rsum0)                           \
            FA_EXP(sb[0], mb[0], paB[0], 0, 1, rsum1)                           \
            FA_EXP(sb[1], mb[1], paB[0], 2, 3, rsum1)                           \
            FA_EXP(sb[2], mb[2], paB[1], 0, 1, rsum1)                           \
            FA_EXP(sb[3], mb[3], paB[1], 2, 3, rsum1)                           \
        }                                                                       \
        { /* second half: kv [64,128) */                                        \
            f32x4 sa[4], sb[4];                                                 \
            FA_QKT_HALF(BUF, 4, sa, sb)                                         \
            FA_EXP(sa[0], mb[4], paA[2], 0, 1, rsum0)                           \
            FA_EXP(sa[1], mb[5], paA[2], 2, 3, rsum0)                           \
            FA_EXP(sa[2], mb[6], paA[3], 0, 1, rsum0)                           \
            FA_EXP(sa[3], mb[7], paA[3], 2, 3, rsum0)                           \
            FA_EXP(sb[0], mb[4], paB[2], 0, 1, rsum1)                           \
            FA_EXP(sb[1], mb[5], paB[2], 2, 3, rsum1)                           \
            FA_EXP(sb[2], mb[6], paB[3], 0, 1, rsum1)                           \
            FA_EXP(sb[3], mb[7], paB[3], 2, 3, rsum1)                           \
        }                                                                       \
        /* PV: 4 sigma-windows of 32 cols; vb shared by both chains */          \
        __builtin_amdgcn_s_setprio(1);                                          \
        _Pragma("unroll")                                                       \
        for (int dt = 0; dt < 2; dt++) {                                        \
            const __hip_bfloat16* vrow = &Vt[BUF][(dt * 16 + l15) * 136];       \
            _Pragma("unroll")                                                   \
            for (int wn = 0; wn < 4; wn++) {                                    \
                bf16x8 vb = *(const bf16x8*)&vrow[wn * 32 + qg * 8];            \
                oaccA[dt] = __builtin_amdgcn_mfma_f32_16x16x32_bf16(            \
                    paA[wn].v, vb, oaccA[dt], 0, 0, 0);                         \
                oaccB[dt] = __builtin_amdgcn_mfma_f32_16x16x32_bf16(            \
                    paB[wn].v, vb, oaccB[dt], 0, 0, 0);                         \
            }                                                                   \
        }                                                                       \
        __builtin_amdgcn_s_setprio(0);                                          \
    }

    for (int kt = 0; kt < SEQ; kt += 256) {
        FA_ITER(kt,       0, kregA, vregA, kregB, vregB)
        FA_ITER(kt + 128, 1, kregB, vregB, kregA, vregA)
    }
#undef FA_ITER
#undef FA_QKT_HALF
#undef FA_EXP

    // row sums: lane (l15,qg) holds partial of row l15 (per qfrag)
    float s0 = rsum0, s1 = rsum1;
    s0 += __shfl_xor(s0, 16, 64);
    s0 += __shfl_xor(s0, 32, 64);
    s1 += __shfl_xor(s1, 16, 64);
    s1 += __shfl_xor(s1, 32, 64);

    // oacc layout: D[m=q][n=d]: row = qg*4+r, col = l15 (+16*dt)
    #pragma unroll
    for (int r = 0; r < 4; r++) {
        float invA = 1.0f / __shfl(s0, qg * 4 + r, 64);
        float invB = 1.0f / __shfl(s1, qg * 4 + r, 64);
        int rowA = q0 + w * 32 + qg * 4 + r;
        int rowB = rowA + 16;
        #pragma unroll
        for (int dt = 0; dt < 2; dt++) {
            O[(size_t)(b * SEQ + rowA) * R_DIM + h * D_K + dt * 16 + l15] =
                __float2bfloat16(oaccA[dt][r] * invA);
            O[(size_t)(b * SEQ + rowB) * R_DIM + h * D_K + dt * 16 + l15] =
                __float2bfloat16(oaccB[dt][r] * invB);
        }
    }
}

// ---------------------------------------------------------------------------
extern "C" void kernel_launch(void* const* d_in, const int* in_sizes, int n_in,
                              void* d_out, int out_size, void* d_ws, size_t ws_size,
                              hipStream_t stream)
{
    const float* x  = (const float*)d_in[0];
    const float* Wq = (const float*)d_in[1];
    const float* bq = (const float*)d_in[2];
    const float* Wk = (const float*)d_in[3];
    const float* bk = (const float*)d_in[4];
    const float* Wv = (const float*)d_in[5];
    const float* bv = (const float*)d_in[6];
    const float* Wo = (const float*)d_in[7];
    const float* bo = (const float*)d_in[8];
    const int* mask = (const int*)d_in[9];
    float* out = (float*)d_out;

    // ws layout (AO aliases xb: xb dead after the QKV GEMM)
    char* p = (char*)d_ws;
    __hip_bfloat16* xb     = (__hip_bfloat16*)p;                       // 16 MB
    __hip_bfloat16* AO     = xb;                                       // 4 MB alias
    __hip_bfloat16* Wqkvb  = (__hip_bfloat16*)(p + (16u << 20));       // 6 MB
    __hip_bfloat16* Wob    = (__hip_bfloat16*)(p + (22u << 20));       // 2 MB
    float*          biasq  = (float*)(p + (24u << 20));                // 6 KB
    float*          mbias  = (float*)(p + (24u << 20) + 8192);         // 16 KB
    __hip_bfloat16* QKVb   = (__hip_bfloat16*)(p + (25u << 20));       // 12 MB

    dim3 blk(256);
    hipLaunchKernelGGL(cvt_inputs, dim3(256, 6), blk, 0, stream,
                       x, xb, Wq, Wk, Wv, Wo, Wqkvb, Wob, bq, bk, bv, biasq, mask, mbias);
    hipLaunchKernelGGL((gemm_dma<true>), dim3(N_QKV / 64, M_ROWS / 128), blk, 0, stream,
                       xb, Wqkvb, biasq, QKVb, N_QKV, D_MODEL);
    hipLaunchKernelGGL(flash_attn11, dim3(B_SZ * N_HEADS * (SEQ / 128)), blk, 0, stream,
                       QKVb, mbias, AO);
    hipLaunchKernelGGL((gemm_dma<false>), dim3(D_MODEL / 64, M_ROWS / 128), blk, 0, stream,
                       AO, Wob, bo, out, D_MODEL, R_DIM);
}

// Round 12
// 187.718 us; speedup vs baseline: 1.1018x; 1.1018x over previous
//
#include <hip/hip_runtime.h>
#include <hip/hip_bf16.h>
#include <math.h>

typedef __attribute__((ext_vector_type(8))) short bf16x8;
typedef __attribute__((ext_vector_type(4))) float f32x4;

#define D_MODEL 2048
#define R_DIM 512
#define N_HEADS 16
#define D_K 32
#define B_SZ 2
#define SEQ 2048
#define M_ROWS (B_SZ * SEQ)
#define N_QKV 1536
// log2(e) / sqrt(D_K) — folded into Wq/bq so attention does raw exp2(Q.K)
#define QSCALE 0.2550627231338903f

// async global->LDS 16B DMA (lane i lands at lds_base + i*16)
__device__ __forceinline__ void dma16(const void* g, void* l)
{
    __builtin_amdgcn_global_load_lds(
        (const __attribute__((address_space(1))) void*)g,
        (__attribute__((address_space(3))) void*)l, 16, 0, 0);
}

// pack two f32 -> one dword of 2 bf16 (lo = first arg). No builtin on gfx950.
__device__ __forceinline__ unsigned cvt_pk_bf16(float lo, float hi)
{
    unsigned r;
    asm("v_cvt_pk_bf16_f32 %0, %1, %2" : "=v"(r) : "v"(lo), "v"(hi));
    return r;
}

// ---------------------------------------------------------------------------
// One-time f32 -> bf16 conversion. 4 loads in flight per thread.
// by: 0 Wq*QSCALE  1 Wk  2 Wv  3 Wo  4 x  5 bias_qkv & mask bias
// ---------------------------------------------------------------------------
__global__ __launch_bounds__(256) void cvt_inputs(
    const float* __restrict__ x,  __hip_bfloat16* __restrict__ xb,
    const float* __restrict__ Wq, const float* __restrict__ Wk,
    const float* __restrict__ Wv, const float* __restrict__ Wo,
    __hip_bfloat16* __restrict__ Wqkvb, __hip_bfloat16* __restrict__ Wob,
    const float* __restrict__ bq, const float* __restrict__ bk,
    const float* __restrict__ bv, float* __restrict__ bias_qkv,
    const int* __restrict__ mask, float* __restrict__ mbias)
{
    const int by = blockIdx.y;
    const int tid = blockIdx.x * blockDim.x + threadIdx.x;
    const int nthr = gridDim.x * blockDim.x;   // 65536
    if (by == 5) {
        for (int i = tid; i < N_QKV; i += nthr) {
            float v = (i < 512) ? bq[i] * QSCALE
                    : (i < 1024) ? bk[i - 512] : bv[i - 1024];
            bias_qkv[i] = v;
        }
        for (int i = tid; i < B_SZ * SEQ; i += nthr)
            mbias[i] = mask[i] ? 0.0f : -1e30f;
        return;
    }
    const float* src; __hip_bfloat16* dst; float sc = 1.0f; int n;
    switch (by) {
      case 0: src = Wq; dst = Wqkvb; sc = QSCALE; n = R_DIM * D_MODEL; break;
      case 1: src = Wk; dst = Wqkvb + (size_t)R_DIM * D_MODEL; n = R_DIM * D_MODEL; break;
      case 2: src = Wv; dst = Wqkvb + (size_t)2 * R_DIM * D_MODEL; n = R_DIM * D_MODEL; break;
      case 3: src = Wo; dst = Wob; n = D_MODEL * R_DIM; break;
      default: src = x;  dst = xb;  n = M_ROWS * D_MODEL; break;
    }
    const float4* s4 = (const float4*)src;
    ushort4* d4 = (ushort4*)dst;
    const int n4 = n >> 2;          // 262144 (W) or 4194304 (x)
    const int step = nthr * 4;      // 262144
    for (int i0 = tid; i0 < n4; i0 += step) {
        float4 f0 = s4[i0];
        float4 f1 = s4[i0 + nthr];
        float4 f2 = s4[i0 + 2 * nthr];
        float4 f3 = s4[i0 + 3 * nthr];
        union { ushort4 u; __hip_bfloat16 h[4]; } r0, r1, r2, r3;
        r0.h[0] = __float2bfloat16(f0.x * sc); r0.h[1] = __float2bfloat16(f0.y * sc);
        r0.h[2] = __float2bfloat16(f0.z * sc); r0.h[3] = __float2bfloat16(f0.w * sc);
        r1.h[0] = __float2bfloat16(f1.x * sc); r1.h[1] = __float2bfloat16(f1.y * sc);
        r1.h[2] = __float2bfloat16(f1.z * sc); r1.h[3] = __float2bfloat16(f1.w * sc);
        r2.h[0] = __float2bfloat16(f2.x * sc); r2.h[1] = __float2bfloat16(f2.y * sc);
        r2.h[2] = __float2bfloat16(f2.z * sc); r2.h[3] = __float2bfloat16(f2.w * sc);
        r3.h[0] = __float2bfloat16(f3.x * sc); r3.h[1] = __float2bfloat16(f3.y * sc);
        r3.h[2] = __float2bfloat16(f3.z * sc); r3.h[3] = __float2bfloat16(f3.w * sc);
        d4[i0]            = r0.u;
        d4[i0 + nthr]     = r1.u;
        d4[i0 + 2 * nthr] = r2.u;
        d4[i0 + 3 * nthr] = r3.u;
    }
}

// ---------------------------------------------------------------------------
// DMA-staged GEMM: C[M,N] = A[M,K] @ W[N,K]^T + bias[N]  (bf16 MFMA, f32 acc)
// BM=128, BN=64, BK=64. 4 waves, wave-tile 64Mx32N (4x2 accs, 16 MFMA/iter).
// Session-final form. Cross-round ledger (R5/R6/R7/R9): this single-buffered
// 128x64 @ (256,4), grid 3+/CU, beats every 128x128 / dbuf / counted-vmcnt
// variant at this problem size — grid residency > per-block density, and the
// 2-phase stage+barrier stall is structural (m233), not removable by vmcnt
// accounting at this occupancy.
// ---------------------------------------------------------------------------
template<bool OUT_BF16>
__global__ __launch_bounds__(256, 4) void gemm_dma(
    const __hip_bfloat16* __restrict__ A,
    const __hip_bfloat16* __restrict__ W,
    const float* __restrict__ bias,
    void* __restrict__ Cv,
    int N, int K)
{
    __shared__ __hip_bfloat16 As[128 * 64];   // 16 KB, slot = row*8 + (c^(row&7))
    __shared__ __hip_bfloat16 Bs[64 * 64];    // 8 KB

    const int tid = threadIdx.x, lane = tid & 63, w = tid >> 6;
    const int l15 = lane & 15, q = lane >> 4;
    const int bm = blockIdx.y * 128, bn = blockIdx.x * 64;
    const int m_off = (w & 1) * 64, n_off = (w >> 1) * 32;

    const int lrow = lane >> 3;            // 0..7
    const int lc   = (lane & 7) ^ lrow;    // swizzled 16B-chunk within row

    f32x4 acc[4][2] = {};

    for (int kt = 0; kt < K; kt += 64) {
        if (kt) __syncthreads();           // all waves done reading prev tile
        #pragma unroll
        for (int j = 0; j < 4; j++) {      // A: 128 rows, 8 rows per issue
            int row = (w * 4 + j) * 8 + lrow;
            dma16(&A[(size_t)(bm + row) * K + kt + lc * 8], &As[(w * 4 + j) * 512]);
        }
        #pragma unroll
        for (int j = 0; j < 2; j++) {      // B: 64 rows
            int row = (w * 2 + j) * 8 + lrow;
            dma16(&W[(size_t)(bn + row) * K + kt + lc * 8], &Bs[(w * 2 + j) * 512]);
        }
        __syncthreads();                   // vmcnt drain + barrier

        #pragma unroll
        for (int ks = 0; ks < 2; ks++) {
            bf16x8 af[4], bf[2];
            #pragma unroll
            for (int t = 0; t < 4; t++) {
                int row = m_off + t * 16 + l15;
                af[t] = *(const bf16x8*)&As[row * 64 + (((ks * 4 + q) ^ (l15 & 7)) * 8)];
            }
            #pragma unroll
            for (int u = 0; u < 2; u++) {
                int row = n_off + u * 16 + l15;
                bf[u] = *(const bf16x8*)&Bs[row * 64 + (((ks * 4 + q) ^ (l15 & 7)) * 8)];
            }
            #pragma unroll
            for (int mt = 0; mt < 4; mt++)
                #pragma unroll
                for (int nt = 0; nt < 2; nt++)
                    acc[mt][nt] = __builtin_amdgcn_mfma_f32_16x16x32_bf16(
                        af[mt], bf[nt], acc[mt][nt], 0, 0, 0);
        }
    }

    #pragma unroll
    for (int mt = 0; mt < 4; mt++) {
        #pragma unroll
        for (int nt = 0; nt < 2; nt++) {
            int gm = bm + m_off + mt * 16 + q * 4;
            int gn = bn + n_off + nt * 16 + l15;
            float bv = bias[gn];
            #pragma unroll
            for (int r = 0; r < 4; r++) {
                float v = acc[mt][nt][r] + bv;
                if (OUT_BF16)
                    ((__hip_bfloat16*)Cv)[(size_t)(gm + r) * N + gn] = __float2bfloat16(v);
                else
                    ((float*)Cv)[(size_t)(gm + r) * N + gn] = v;
            }
        }
    }
}

// ---------------------------------------------------------------------------
// Flash attention v8: QBLK 128 (2 Q-fragments per wave), KVBLK 64.
// Session-final form — the measured TLP x ILP x register-pressure optimum:
//   QBLK 64 -> 53us, 128 -> ~40us, 256 -> 64us (R10);
//   KVBLK 128 -> 53us (R11, VGPR 96 + occupancy 16%);
//   K-split for occupancy -> neutral (R4, residency caps ~31%).
// Register-P via swapped QK^T + cvt_pk under slot-relabel sigma (no P LDS
// round-trip); K/V reg-prefetched right after the barrier (full-iteration
// latency cover); one barrier per tile; sigma-permuted V^T so each PV
// B-operand is one ds_read_b128.
// ---------------------------------------------------------------------------
__global__ __launch_bounds__(256, 4) void flash_attn8(
    const __hip_bfloat16* __restrict__ QKV,
    const float* __restrict__ mbias,
    __hip_bfloat16* __restrict__ O)
{
    __shared__ __hip_bfloat16 Ks[2][64 * 40];   // 10 KB
    __shared__ __hip_bfloat16 Vt[2][32 * 72];   // 9 KB (sigma-permuted cols)

    const int tid = threadIdx.x, lane = tid & 63, w = tid >> 6;
    const int l15 = lane & 15, qg = lane >> 4;

    // XCD-chunked swizzle (512 % 8 == 0 -> bijective)
    const int nwg = (int)gridDim.x;
    const int swz = ((int)blockIdx.x & 7) * (nwg >> 3) + ((int)blockIdx.x >> 3);
    const int qt = swz & 15;
    const int h  = (swz >> 4) & 15;
    const int b  = swz >> 8;
    const int q0 = qt * 128;

    // Q fragments (B-operand of swapped QK^T): rows q0+w*32+{l15, 16+l15}
    const bf16x8 qa0 = *(const bf16x8*)
        &QKV[(size_t)(b * SEQ + q0 + w * 32 + l15) * N_QKV + h * D_K + qg * 8];
    const bf16x8 qa1 = *(const bf16x8*)
        &QKV[(size_t)(b * SEQ + q0 + w * 32 + 16 + l15) * N_QKV + h * D_K + qg * 8];

    const int kv_k = tid >> 2, d0_k = (tid & 3) * 8;   // K staging coords
    const int kv_v = tid & 63, d0_v = (tid >> 6) * 8;  // V staging coords
    // sigma-permuted V column: kv = 32a+16hi+4g+r  ->  scol = 32a+8g+4hi+r
    const int scol_v = (kv_v & 32) + ((kv_v >> 2) & 3) * 8
                     + ((kv_v >> 4) & 1) * 4 + (kv_v & 3);

    const __hip_bfloat16* Kp = QKV + (size_t)b * SEQ * N_QKV + R_DIM + h * D_K;
    const __hip_bfloat16* Vp = QKV + (size_t)b * SEQ * N_QKV + 2 * R_DIM + h * D_K;
    const float* mb_base = mbias + b * SEQ;

    f32x4 oaccA[2] = {};   // qfrag0: rows w*32 + qg*4+r (+0)
    f32x4 oaccB[2] = {};   // qfrag1: rows w*32 + 16 + qg*4+r
    float rsum0 = 0.f, rsum1 = 0.f;

    uint4 kregA, kregB, vregA, vregB;

    // prologue: tile 0 into register set A
    kregA = *(const uint4*)&Kp[(size_t)kv_k * N_QKV + d0_k];
    vregA = *(const uint4*)&Vp[(size_t)kv_v * N_QKV + d0_v];

#define FA_EXP(SC, MB, PA, U0, U1, RS)                                          \
    {                                                                           \
        float p0 = __builtin_amdgcn_exp2f(SC[0] + MB.x);                        \
        float p1 = __builtin_amdgcn_exp2f(SC[1] + MB.y);                        \
        float p2 = __builtin_amdgcn_exp2f(SC[2] + MB.z);                        \
        float p3 = __builtin_amdgcn_exp2f(SC[3] + MB.w);                        \
        RS += (p0 + p1) + (p2 + p3);                                            \
        PA.u[U0] = cvt_pk_bf16(p0, p1);                                         \
        PA.u[U1] = cvt_pk_bf16(p2, p3);                                         \
    }

#define FA_ITER(KT, BUF, KREG, VREG, KREGN, VREGN)                              \
    {                                                                           \
        /* stage current tile (regs loaded last iter) into LDS[BUF] */          \
        *(uint4*)&Ks[BUF][kv_k * 40 + d0_k] = KREG;                             \
        { union { uint4 u; __hip_bfloat16 hv[8]; } vv; vv.u = VREG;             \
          _Pragma("unroll")                                                     \
          for (int j = 0; j < 8; j++)                                           \
              Vt[BUF][(d0_v + j) * 72 + scol_v] = vv.hv[j]; }                   \
        __syncthreads();                                                        \
        /* mask bias FIRST (oldest vmcnt) so its wait doesn't drain prefetch */ \
        float4 mb0 = *(const float4*)&mb_base[(KT) +  0 + qg * 4];              \
        float4 mb1 = *(const float4*)&mb_base[(KT) + 16 + qg * 4];              \
        float4 mb2 = *(const float4*)&mb_base[(KT) + 32 + qg * 4];              \
        float4 mb3 = *(const float4*)&mb_base[(KT) + 48 + qg * 4];              \
        /* prefetch next tile: a full iteration of compute covers it */         \
        if ((KT) + 64 < SEQ) {                                                  \
            KREGN = *(const uint4*)&Kp[(size_t)((KT) + 64 + kv_k) * N_QKV + d0_k]; \
            VREGN = *(const uint4*)&Vp[(size_t)((KT) + 64 + kv_v) * N_QKV + d0_v]; \
        }                                                                       \
        /* swapped QK^T: kb shared by both Q fragments */                       \
        f32x4 a0, a1, a2, a3, b0, b1, b2, b3;                                   \
        __builtin_amdgcn_s_setprio(1);                                          \
        { bf16x8 kb = *(const bf16x8*)&Ks[BUF][( 0 + l15) * 40 + qg * 8];       \
          f32x4 z = {};                                                         \
          a0 = __builtin_amdgcn_mfma_f32_16x16x32_bf16(kb, qa0, z, 0, 0, 0);    \
          b0 = __builtin_amdgcn_mfma_f32_16x16x32_bf16(kb, qa1, z, 0, 0, 0); }  \
        { bf16x8 kb = *(const bf16x8*)&Ks[BUF][(16 + l15) * 40 + qg * 8];       \
          f32x4 z = {};                                                         \
          a1 = __builtin_amdgcn_mfma_f32_16x16x32_bf16(kb, qa0, z, 0, 0, 0);    \
          b1 = __builtin_amdgcn_mfma_f32_16x16x32_bf16(kb, qa1, z, 0, 0, 0); }  \
        { bf16x8 kb = *(const bf16x8*)&Ks[BUF][(32 + l15) * 40 + qg * 8];       \
          f32x4 z = {};                                                         \
          a2 = __builtin_amdgcn_mfma_f32_16x16x32_bf16(kb, qa0, z, 0, 0, 0);    \
          b2 = __builtin_amdgcn_mfma_f32_16x16x32_bf16(kb, qa1, z, 0, 0, 0); }  \
        { bf16x8 kb = *(const bf16x8*)&Ks[BUF][(48 + l15) * 40 + qg * 8];       \
          f32x4 z = {};                                                         \
          a3 = __builtin_amdgcn_mfma_f32_16x16x32_bf16(kb, qa0, z, 0, 0, 0);    \
          b3 = __builtin_amdgcn_mfma_f32_16x16x32_bf16(kb, qa1, z, 0, 0, 0); }  \
        __builtin_amdgcn_s_setprio(0);                                          \
        /* exp2 + pack: lane's own dwords ARE the PV A-frag under sigma */      \
        union { unsigned u[4]; bf16x8 v; } paA0, paA1, paB0, paB1;              \
        FA_EXP(a0, mb0, paA0, 0, 1, rsum0)                                      \
        FA_EXP(a1, mb1, paA0, 2, 3, rsum0)                                      \
        FA_EXP(a2, mb2, paA1, 0, 1, rsum0)                                      \
        FA_EXP(a3, mb3, paA1, 2, 3, rsum0)                                      \
        FA_EXP(b0, mb0, paB0, 0, 1, rsum1)                                      \
        FA_EXP(b1, mb1, paB0, 2, 3, rsum1)                                      \
        FA_EXP(b2, mb2, paB1, 0, 1, rsum1)                                      \
        FA_EXP(b3, mb3, paB1, 2, 3, rsum1)                                      \
        /* PV: sigma-permuted Vt; vb shared by both Q fragments */              \
        __builtin_amdgcn_s_setprio(1);                                          \
        _Pragma("unroll")                                                       \
        for (int dt = 0; dt < 2; dt++) {                                        \
            const __hip_bfloat16* vrow = &Vt[BUF][(dt * 16 + l15) * 72];        \
            bf16x8 vb0 = *(const bf16x8*)&vrow[qg * 8];                         \
            bf16x8 vb1 = *(const bf16x8*)&vrow[32 + qg * 8];                    \
            oaccA[dt] = __builtin_amdgcn_mfma_f32_16x16x32_bf16(paA0.v, vb0, oaccA[dt], 0, 0, 0); \
            oaccA[dt] = __builtin_amdgcn_mfma_f32_16x16x32_bf16(paA1.v, vb1, oaccA[dt], 0, 0, 0); \
            oaccB[dt] = __builtin_amdgcn_mfma_f32_16x16x32_bf16(paB0.v, vb0, oaccB[dt], 0, 0, 0); \
            oaccB[dt] = __builtin_amdgcn_mfma_f32_16x16x32_bf16(paB1.v, vb1, oaccB[dt], 0, 0, 0); \
        }                                                                       \
        __builtin_amdgcn_s_setprio(0);                                          \
    }

    for (int kt = 0; kt < SEQ; kt += 128) {
        FA_ITER(kt,      0, kregA, vregA, kregB, vregB)
        FA_ITER(kt + 64, 1, kregB, vregB, kregA, vregA)
    }
#undef FA_ITER
#undef FA_EXP

    // row sums: lane (l15,qg) holds partial of row l15 (per qfrag)
    float s0 = rsum0, s1 = rsum1;
    s0 += __shfl_xor(s0, 16, 64);
    s0 += __shfl_xor(s0, 32, 64);
    s1 += __shfl_xor(s1, 16, 64);
    s1 += __shfl_xor(s1, 32, 64);

    // oacc layout: D[m=q][n=d]: row = qg*4+r, col = l15 (+16*dt)
    #pragma unroll
    for (int r = 0; r < 4; r++) {
        float invA = 1.0f / __shfl(s0, qg * 4 + r, 64);
        float invB = 1.0f / __shfl(s1, qg * 4 + r, 64);
        int rowA = q0 + w * 32 + qg * 4 + r;
        int rowB = rowA + 16;
        #pragma unroll
        for (int dt = 0; dt < 2; dt++) {
            O[(size_t)(b * SEQ + rowA) * R_DIM + h * D_K + dt * 16 + l15] =
                __float2bfloat16(oaccA[dt][r] * invA);
            O[(size_t)(b * SEQ + rowB) * R_DIM + h * D_K + dt * 16 + l15] =
                __float2bfloat16(oaccB[dt][r] * invB);
        }
    }
}

// ---------------------------------------------------------------------------
extern "C" void kernel_launch(void* const* d_in, const int* in_sizes, int n_in,
                              void* d_out, int out_size, void* d_ws, size_t ws_size,
                              hipStream_t stream)
{
    const float* x  = (const float*)d_in[0];
    const float* Wq = (const float*)d_in[1];
    const float* bq = (const float*)d_in[2];
    const float* Wk = (const float*)d_in[3];
    const float* bk = (const float*)d_in[4];
    const float* Wv = (const float*)d_in[5];
    const float* bv = (const float*)d_in[6];
    const float* Wo = (const float*)d_in[7];
    const float* bo = (const float*)d_in[8];
    const int* mask = (const int*)d_in[9];
    float* out = (float*)d_out;

    // ws layout (AO aliases xb: xb dead after the QKV GEMM)
    char* p = (char*)d_ws;
    __hip_bfloat16* xb     = (__hip_bfloat16*)p;                       // 16 MB
    __hip_bfloat16* AO     = xb;                                       // 4 MB alias
    __hip_bfloat16* Wqkvb  = (__hip_bfloat16*)(p + (16u << 20));       // 6 MB
    __hip_bfloat16* Wob    = (__hip_bfloat16*)(p + (22u << 20));       // 2 MB
    float*          biasq  = (float*)(p + (24u << 20));                // 6 KB
    float*          mbias  = (float*)(p + (24u << 20) + 8192);         // 16 KB
    __hip_bfloat16* QKVb   = (__hip_bfloat16*)(p + (25u << 20));       // 12 MB

    dim3 blk(256);
    hipLaunchKernelGGL(cvt_inputs, dim3(256, 6), blk, 0, stream,
                       x, xb, Wq, Wk, Wv, Wo, Wqkvb, Wob, bq, bk, bv, biasq, mask, mbias);
    hipLaunchKernelGGL((gemm_dma<true>), dim3(N_QKV / 64, M_ROWS / 128), blk, 0, stream,
                       xb, Wqkvb, biasq, QKVb, N_QKV, D_MODEL);
    hipLaunchKernelGGL(flash_attn8, dim3(B_SZ * N_HEADS * (SEQ / 128)), blk, 0, stream,
                       QKVb, mbias, AO);
    hipLaunchKernelGGL((gemm_dma<false>), dim3(D_MODEL / 64, M_ROWS / 128), blk, 0, stream,
                       AO, Wob, bo, out, D_MODEL, R_DIM);
}